// Round 1
// baseline (823.478 us; speedup 1.0000x reference)
//
#include <hip/hip_runtime.h>

// Problem: B=256, N=1000, D=128, H=8, dk=16
// out[b,n] = log_softmax over n of masked tanh-clipped pointer logits.
//
// Restructured math (removes the 393MB kvl intermediate):
//   qkp[b,h,c]  = 0.25 * sum_e W_node[c, h*16+e] * q[b, h*16+e]
//   compat[b,h,n] = sum_c E[b,n,c] * qkp[b,h,c]           (masked -> -1e9)
//   Ebar[b,h,c] = sum_n softmax_n(compat)[h,n] * E[b,n,c] (online softmax)
//   heads -> glimpse -> gl_proj[b,c] = (1/sqrt(128)) sum_d W_node[c,256+d]*glimpse[b,d]
//   logits[b,n] = sum_c E[b,n,c] * gl_proj[b,c]; z=10*tanh; mask; log_softmax.
//
// ws layout: qkp (256*1024 f32 = 1MB) | glp (256*128 f32 = 128KB) | mask-format flag (int)
// ws requirement: ~1.2 MB.

#define NEG (-1e9f)

// ---------------------------------------------------------------------------
// Kernel 0: detect mask storage format. int32 upload => bytes at offsets
// (i%4)!=0 within the first 256000 bytes are all zero. bool upload => ~96K
// nonzero bytes there. Writes flag (1 = byte format) to ws.
__global__ void k_detect(const unsigned char* __restrict__ mb, int* __restrict__ flag)
{
    __shared__ int any_s;
    if (threadIdx.x == 0) any_s = 0;
    __syncthreads();
    int local = 0;
    for (int i = threadIdx.x; i < 256000; i += 256)
        if ((i & 3) && mb[i]) local = 1;
    if (local) atomicOr(&any_s, 1);
    __syncthreads();
    if (threadIdx.x == 0) *flag = any_s;
}

// ---------------------------------------------------------------------------
// Kernel 1: per-b precompute: graph mean, q = fixed_ctx + step_ctx@W_step,
// then qkp[b,h,c]. grid=256 blocks, 256 threads.
__global__ __launch_bounds__(256) void k_pre(
    const float* __restrict__ E, const float* __restrict__ Wn,
    const float* __restrict__ Wf, const float* __restrict__ Ws,
    const int* __restrict__ fi, const int* __restrict__ li,
    float* __restrict__ qkp)
{
    const int b = blockIdx.x;
    const int t = threadIdx.x;
    __shared__ float mu[128];
    __shared__ float e1[128], e2[128];
    __shared__ float q[128];
    __shared__ float4 red4[256];

    const float4* E4 = (const float4*)(E + (size_t)b * 128000);

    // mean over n: thread (c4 = t&31, slice = t>>5), coalesced float4 loads
    {
        const int c4 = t & 31, s = t >> 5;
        float4 acc = make_float4(0.f, 0.f, 0.f, 0.f);
        for (int r = s; r < 1000; r += 8) {
            float4 v = E4[r * 32 + c4];
            acc.x += v.x; acc.y += v.y; acc.z += v.z; acc.w += v.w;
        }
        red4[t] = acc;
    }
    __syncthreads();
    if (t < 32) {
        float4 acc = red4[t];
        #pragma unroll
        for (int s = 1; s < 8; ++s) {
            float4 v = red4[t + 32 * s];
            acc.x += v.x; acc.y += v.y; acc.z += v.z; acc.w += v.w;
        }
        const float inv = 1.0f / 1000.0f;
        ((float4*)mu)[t] = make_float4(acc.x * inv, acc.y * inv, acc.z * inv, acc.w * inv);
    }
    if (t >= 64 && t < 96) {
        ((float4*)e1)[t - 64] = E4[fi[b] * 32 + (t - 64)];
    } else if (t >= 96 && t < 128) {
        ((float4*)e2)[t - 96] = E4[li[b] * 32 + (t - 96)];
    }
    __syncthreads();
    // q[d] = mu@W_fixed + e1@W_step[0:128] + e2@W_step[128:256]
    if (t < 128) {
        float acc = 0.f;
        for (int c = 0; c < 128; ++c) acc += mu[c] * Wf[c * 128 + t];
        for (int c = 0; c < 128; ++c) acc += e1[c] * Ws[c * 128 + t];
        for (int c = 0; c < 128; ++c) acc += e2[c] * Ws[(128 + c) * 128 + t];
        q[t] = acc;
    }
    __syncthreads();
    // qkp[h][c] = 0.25 * sum_e Wn[c*384 + h*16+e] * q[h*16+e]
    // lanes along j (coalesced Wn reads), 16-lane shuffle reduce per head.
    {
        const int j = t & 127, cg = t >> 7;
        const float qj = q[j];
        for (int c0 = 0; c0 < 128; c0 += 2) {
            const int c = c0 + cg;
            float v = Wn[c * 384 + j] * qj;
            v += __shfl_down(v, 8, 16);
            v += __shfl_down(v, 4, 16);
            v += __shfl_down(v, 2, 16);
            v += __shfl_down(v, 1, 16);
            if ((j & 15) == 0) qkp[b * 1024 + (j >> 4) * 128 + c] = v * 0.25f;
        }
    }
}

// ---------------------------------------------------------------------------
// Kernel 2: fused masked multi-head glimpse attention via online softmax over
// 64-row tiles; epilogue computes glimpse and gl_proj. grid=256, 256 threads.
__global__ __launch_bounds__(256) void k_glimpse(
    const float* __restrict__ E, const float* __restrict__ Wn,
    const float* __restrict__ Wo,
    const int* __restrict__ maskI, const unsigned char* __restrict__ maskB,
    const int* __restrict__ flag,
    const float* __restrict__ qkp, float* __restrict__ glp)
{
    const int b = blockIdx.x;
    const int t = threadIdx.x;
    __shared__ float4 qk4[256];      // qkp, groups xor-swizzled g^(g>>3)
    __shared__ float4 Et[2048];      // E tile [64 rows][32 groups], swizzled g^(r&7)
    __shared__ float pc[64 * 33];    // partial compat [row][q*8+h], pad 33
    __shared__ float ct[64 * 9];     // compat [row][h], pad 9
    __shared__ float pt[64 * 8];     // p [row][h] (float4-readable)
    __shared__ float mh[8], lh[8], al[8];
    __shared__ float EbarF[8 * 128];
    __shared__ float heads[128];
    __shared__ float gl[128];

    const float4* E4 = (const float4*)(E + (size_t)b * 128000);
    const bool useB = (*flag != 0);

    {   // load + swizzle qkp
        const int h = t >> 5, g = t & 31;
        qk4[h * 32 + (g ^ (g >> 3))] = ((const float4*)(qkp + b * 1024))[t];
    }
    if (t < 8) { mh[t] = -3e38f; lh[t] = 0.f; }
    float4 eacc[8];
    #pragma unroll
    for (int h = 0; h < 8; ++h) eacc[h] = make_float4(0.f, 0.f, 0.f, 0.f);
    const int c4 = t & 31, sl = t >> 5;   // Ebar mapping
    const int rr = t >> 2, qq = t & 3;    // stage mapping: quarter-rows
    __syncthreads();

    for (int tile = 0; tile < 16; ++tile) {
        const int r0 = tile * 64;
        // ---- stage tile to LDS + partial compat in-registers ----
        {
            const int g = r0 + rr;
            float4 v[8];
            if (g < 1000) {
                #pragma unroll
                for (int i = 0; i < 8; ++i) v[i] = E4[g * 32 + qq * 8 + i];
            } else {
                #pragma unroll
                for (int i = 0; i < 8; ++i) v[i] = make_float4(0.f, 0.f, 0.f, 0.f);
            }
            float pch[8];
            #pragma unroll
            for (int h = 0; h < 8; ++h) pch[h] = 0.f;
            #pragma unroll
            for (int i = 0; i < 8; ++i) {
                const int grp = qq * 8 + i;
                Et[rr * 32 + (grp ^ (rr & 7))] = v[i];
                #pragma unroll
                for (int h = 0; h < 8; ++h) {
                    float4 w = qk4[h * 32 + (grp ^ qq)];
                    pch[h] += v[i].x * w.x + v[i].y * w.y + v[i].z * w.z + v[i].w * w.w;
                }
            }
            #pragma unroll
            for (int h = 0; h < 8; ++h) pc[rr * 33 + qq * 8 + h] = pch[h];
        }
        __syncthreads();
        // ---- reduce quarters, apply mask ----
        #pragma unroll
        for (int k = 0; k < 2; ++k) {
            const int idx = t + k * 256;
            const int row = idx >> 3, h = idx & 7;
            float s = pc[row * 33 + h] + pc[row * 33 + 8 + h]
                    + pc[row * 33 + 16 + h] + pc[row * 33 + 24 + h];
            const int g = r0 + row;
            const bool m = (g >= 1000) ||
                (useB ? (maskB[b * 1000 + g] != 0) : (maskI[b * 1000 + g] != 0));
            ct[row * 9 + h] = m ? NEG : s;
        }
        __syncthreads();
        // ---- per-head running max + rescale factor ----
        if (t < 8) {
            float mt = -3e38f;
            for (int r = 0; r < 64; ++r) mt = fmaxf(mt, ct[r * 9 + t]);
            const float mnew = fmaxf(mh[t], mt);
            al[t] = __expf(mh[t] - mnew);
            mh[t] = mnew;
        }
        __syncthreads();
        // ---- p = exp(compat - m) ----
        #pragma unroll
        for (int k = 0; k < 2; ++k) {
            const int idx = t + k * 256;
            const int row = idx >> 3, h = idx & 7;
            pt[row * 8 + h] = __expf(ct[row * 9 + h] - mh[h]);
        }
        __syncthreads();
        // ---- l update + Ebar accumulate (slice of 8 rows per thread) ----
        if (t < 8) {
            float s = 0.f;
            for (int r = 0; r < 64; ++r) s += pt[r * 8 + t];
            lh[t] = lh[t] * al[t] + s;
        }
        {
            #pragma unroll
            for (int h = 0; h < 8; ++h) {
                const float a = al[h];
                eacc[h].x *= a; eacc[h].y *= a; eacc[h].z *= a; eacc[h].w *= a;
            }
            #pragma unroll
            for (int j = 0; j < 8; ++j) {
                const int r = sl * 8 + j;
                const float4 ev = Et[r * 32 + (c4 ^ (r & 7))];
                const float4 p0 = ((float4*)pt)[r * 2];
                const float4 p1 = ((float4*)pt)[r * 2 + 1];
                eacc[0].x += p0.x * ev.x; eacc[0].y += p0.x * ev.y; eacc[0].z += p0.x * ev.z; eacc[0].w += p0.x * ev.w;
                eacc[1].x += p0.y * ev.x; eacc[1].y += p0.y * ev.y; eacc[1].z += p0.y * ev.z; eacc[1].w += p0.y * ev.w;
                eacc[2].x += p0.z * ev.x; eacc[2].y += p0.z * ev.y; eacc[2].z += p0.z * ev.z; eacc[2].w += p0.z * ev.w;
                eacc[3].x += p0.w * ev.x; eacc[3].y += p0.w * ev.y; eacc[3].z += p0.w * ev.z; eacc[3].w += p0.w * ev.w;
                eacc[4].x += p1.x * ev.x; eacc[4].y += p1.x * ev.y; eacc[4].z += p1.x * ev.z; eacc[4].w += p1.x * ev.w;
                eacc[5].x += p1.y * ev.x; eacc[5].y += p1.y * ev.y; eacc[5].z += p1.y * ev.z; eacc[5].w += p1.y * ev.w;
                eacc[6].x += p1.z * ev.x; eacc[6].y += p1.z * ev.y; eacc[6].z += p1.z * ev.z; eacc[6].w += p1.z * ev.w;
                eacc[7].x += p1.w * ev.x; eacc[7].y += p1.w * ev.y; eacc[7].z += p1.w * ev.z; eacc[7].w += p1.w * ev.w;
            }
        }
        __syncthreads();
    }

    // ---- reduce 8 slice-partials (reuse Et as scratch), fold 1/l ----
    #pragma unroll
    for (int h = 0; h < 8; ++h) Et[sl * 256 + h * 32 + c4] = eacc[h];
    __syncthreads();
    {
        const int h = t >> 5, cc = t & 31;
        float4 s = make_float4(0.f, 0.f, 0.f, 0.f);
        #pragma unroll
        for (int s2 = 0; s2 < 8; ++s2) {
            float4 v = Et[s2 * 256 + h * 32 + cc];
            s.x += v.x; s.y += v.y; s.z += v.z; s.w += v.w;
        }
        const float invl = 1.0f / lh[h];
        ((float4*)EbarF)[h * 32 + cc] =
            make_float4(s.x * invl, s.y * invl, s.z * invl, s.w * invl);
    }
    __syncthreads();
    // heads[j] = sum_c EbarF[h(j)][c] * Wn[c*384 + 128 + j]
    if (t < 128) {
        const int h = t >> 4;
        float acc = 0.f;
        for (int c = 0; c < 128; ++c) acc += EbarF[h * 128 + c] * Wn[c * 384 + 128 + t];
        heads[t] = acc;
    }
    __syncthreads();
    if (t < 128) {
        float acc = 0.f;
        for (int j2 = 0; j2 < 128; ++j2) acc += heads[j2] * Wo[j2 * 128 + t];
        gl[t] = acc;
    }
    __syncthreads();
    if (t < 128) {
        float acc = 0.f;
        for (int d2 = 0; d2 < 128; ++d2) acc += Wn[t * 384 + 256 + d2] * gl[d2];
        glp[b * 128 + t] = acc * 0.08838834764831845f; // 1/sqrt(128)
    }
}

// ---------------------------------------------------------------------------
// Kernel 3: logits = E@gl_proj, tanh clip, mask, log_softmax. grid=256.
__global__ __launch_bounds__(256) void k_logits(
    const float* __restrict__ E,
    const int* __restrict__ maskI, const unsigned char* __restrict__ maskB,
    const int* __restrict__ flag,
    const float* __restrict__ glp, float* __restrict__ out)
{
    const int b = blockIdx.x;
    const int t = threadIdx.x;
    __shared__ float gl[128];
    __shared__ float z[1024];
    __shared__ float pc[256];
    __shared__ float red[4];
    __shared__ float stat[2];

    const float4* E4 = (const float4*)(E + (size_t)b * 128000);
    const bool useB = (*flag != 0);
    if (t < 32) ((float4*)gl)[t] = ((const float4*)(glp + b * 128))[t];
    __syncthreads();

    const int rr = t >> 2, qq = t & 3;
    for (int tile = 0; tile < 16; ++tile) {
        const int g = tile * 64 + rr;
        float acc = 0.f;
        if (g < 1000) {
            #pragma unroll
            for (int i = 0; i < 8; ++i) {
                const float4 v = E4[g * 32 + qq * 8 + i];
                const float4 w = ((float4*)gl)[qq * 8 + i];
                acc += v.x * w.x + v.y * w.y + v.z * w.z + v.w * w.w;
            }
        }
        pc[t] = acc;
        __syncthreads();
        if (t < 64) {
            const int g2 = tile * 64 + t;
            if (g2 < 1000) {
                const float s = pc[t * 4] + pc[t * 4 + 1] + pc[t * 4 + 2] + pc[t * 4 + 3];
                float zz = 10.0f * tanhf(s);
                const bool m = useB ? (maskB[b * 1000 + g2] != 0)
                                    : (maskI[b * 1000 + g2] != 0);
                if (m) zz = NEG;
                z[g2] = zz;
            }
        }
        __syncthreads();
    }
    // block max
    float mloc = -3e38f;
    for (int idx = t; idx < 1000; idx += 256) mloc = fmaxf(mloc, z[idx]);
    #pragma unroll
    for (int off = 32; off > 0; off >>= 1) mloc = fmaxf(mloc, __shfl_down(mloc, off, 64));
    if ((t & 63) == 0) red[t >> 6] = mloc;
    __syncthreads();
    if (t == 0) stat[0] = fmaxf(fmaxf(red[0], red[1]), fmaxf(red[2], red[3]));
    __syncthreads();
    const float zmax = stat[0];
    float sloc = 0.f;
    for (int idx = t; idx < 1000; idx += 256) sloc += __expf(z[idx] - zmax);
    #pragma unroll
    for (int off = 32; off > 0; off >>= 1) sloc += __shfl_down(sloc, off, 64);
    if ((t & 63) == 0) red[t >> 6] = sloc;
    __syncthreads();
    if (t == 0) stat[1] = zmax + __logf(red[0] + red[1] + red[2] + red[3]);
    __syncthreads();
    const float lse = stat[1];
    for (int idx = t; idx < 1000; idx += 256)
        out[(size_t)b * 1000 + idx] = z[idx] - lse;
}

// ---------------------------------------------------------------------------
extern "C" void kernel_launch(void* const* d_in, const int* in_sizes, int n_in,
                              void* d_out, int out_size, void* d_ws, size_t ws_size,
                              hipStream_t stream) {
    const float* E  = (const float*)d_in[0];
    const float* Wn = (const float*)d_in[1];
    const float* Wf = (const float*)d_in[2];
    const float* Ws = (const float*)d_in[3];
    const float* Wo = (const float*)d_in[4];
    const int*   fi = (const int*)d_in[5];
    const int*   li = (const int*)d_in[6];
    const int*   maskI = (const int*)d_in[7];
    const unsigned char* maskB = (const unsigned char*)d_in[7];
    float* out = (float*)d_out;

    float* qkp = (float*)d_ws;                       // 256*1024 floats
    float* glp = qkp + 256 * 1024;                   // 256*128 floats
    int*   flag = (int*)(glp + 256 * 128);           // 1 int

    k_detect<<<1, 256, 0, stream>>>(maskB, flag);
    k_pre<<<256, 256, 0, stream>>>(E, Wn, Wf, Ws, fi, li, qkp);
    k_glimpse<<<256, 256, 0, stream>>>(E, Wn, Wo, maskI, maskB, flag, qkp, glp);
    k_logits<<<256, 256, 0, stream>>>(E, maskI, maskB, flag, glp, out);
}

// Round 2
// 399.228 us; speedup vs baseline: 2.0627x; 2.0627x over previous
//
#include <hip/hip_runtime.h>

// Problem: B=256, N=1000, D=128, H=8, dk=16
// out[b,n] = log_softmax over n of masked tanh-clipped pointer logits.
//
// Restructured math (removes the 393MB kvl intermediate):
//   qkp[b,h,c]  = 0.25 * sum_e W_node[c, h*16+e] * q[b, h*16+e]
//   compat[b,h,n] = sum_c E[b,n,c] * qkp[b,h,c]           (masked -> -1e9)
//   Ebar[b,h,c] = sum_n softmax_n(compat)[h,n] * E[b,n,c] (online softmax)
//   heads -> glimpse -> gl_proj[b,c] = (1/sqrt(128)) sum_d W_node[c,256+d]*glimpse[b,d]
//   logits[b,n] = sum_c E[b,n,c] * gl_proj[b,c]; z=10*tanh; mask; log_softmax.
//
// ws layout: qkp (256*1024 f32 = 1MB) | glp (256*128 f32 = 128KB) | mask-format flag (int)

#define NEG (-1e9f)

// ---------------------------------------------------------------------------
// Kernel 0: detect mask storage format. int32 upload => every 4-byte word is
// 0 or 1 => (word & 0xFFFFFF00) == 0. Byte upload => mask bytes (~50% ones)
// land in upper bytes => nonzero with overwhelming probability over 16 KB.
// R1 fix: was a serial byte-scan of 256000 bytes (427 us!); now 16 KB of
// vectorized uint4 loads, 4 independent loads/thread, one block.
__global__ void k_detect(const uint4* __restrict__ mw, int* __restrict__ flag)
{
    __shared__ int any_s;
    if (threadIdx.x == 0) any_s = 0;
    __syncthreads();
    unsigned acc = 0;
    #pragma unroll
    for (int i = 0; i < 4; ++i) {
        const uint4 v = mw[i * 256 + threadIdx.x];   // 16 KB total
        acc |= (v.x | v.y | v.z | v.w) & 0xFFFFFF00u;
    }
    if (acc) atomicOr(&any_s, 1);
    __syncthreads();
    if (threadIdx.x == 0) *flag = any_s;
}

// ---------------------------------------------------------------------------
// Kernel 1: per-b precompute: graph mean, q = fixed_ctx + step_ctx@W_step,
// then qkp[b,h,c]. grid=256 blocks, 256 threads.
__global__ __launch_bounds__(256) void k_pre(
    const float* __restrict__ E, const float* __restrict__ Wn,
    const float* __restrict__ Wf, const float* __restrict__ Ws,
    const int* __restrict__ fi, const int* __restrict__ li,
    float* __restrict__ qkp)
{
    const int b = blockIdx.x;
    const int t = threadIdx.x;
    __shared__ float mu[128];
    __shared__ float e1[128], e2[128];
    __shared__ float q[128];
    __shared__ float4 red4[256];

    const float4* E4 = (const float4*)(E + (size_t)b * 128000);

    // mean over n: thread (c4 = t&31, slice = t>>5), coalesced float4 loads
    {
        const int c4 = t & 31, s = t >> 5;
        float4 acc = make_float4(0.f, 0.f, 0.f, 0.f);
        for (int r = s; r < 1000; r += 8) {
            float4 v = E4[r * 32 + c4];
            acc.x += v.x; acc.y += v.y; acc.z += v.z; acc.w += v.w;
        }
        red4[t] = acc;
    }
    __syncthreads();
    if (t < 32) {
        float4 acc = red4[t];
        #pragma unroll
        for (int s = 1; s < 8; ++s) {
            float4 v = red4[t + 32 * s];
            acc.x += v.x; acc.y += v.y; acc.z += v.z; acc.w += v.w;
        }
        const float inv = 1.0f / 1000.0f;
        ((float4*)mu)[t] = make_float4(acc.x * inv, acc.y * inv, acc.z * inv, acc.w * inv);
    }
    if (t >= 64 && t < 96) {
        ((float4*)e1)[t - 64] = E4[fi[b] * 32 + (t - 64)];
    } else if (t >= 96 && t < 128) {
        ((float4*)e2)[t - 96] = E4[li[b] * 32 + (t - 96)];
    }
    __syncthreads();
    // q[d] = mu@W_fixed + e1@W_step[0:128] + e2@W_step[128:256]
    if (t < 128) {
        float acc = 0.f;
        for (int c = 0; c < 128; ++c) acc += mu[c] * Wf[c * 128 + t];
        for (int c = 0; c < 128; ++c) acc += e1[c] * Ws[c * 128 + t];
        for (int c = 0; c < 128; ++c) acc += e2[c] * Ws[(128 + c) * 128 + t];
        q[t] = acc;
    }
    __syncthreads();
    // qkp[h][c] = 0.25 * sum_e Wn[c*384 + h*16+e] * q[h*16+e]
    // lanes along j (coalesced Wn reads), 16-lane shuffle reduce per head.
    {
        const int j = t & 127, cg = t >> 7;
        const float qj = q[j];
        for (int c0 = 0; c0 < 128; c0 += 2) {
            const int c = c0 + cg;
            float v = Wn[c * 384 + j] * qj;
            v += __shfl_down(v, 8, 16);
            v += __shfl_down(v, 4, 16);
            v += __shfl_down(v, 2, 16);
            v += __shfl_down(v, 1, 16);
            if ((j & 15) == 0) qkp[b * 1024 + (j >> 4) * 128 + c] = v * 0.25f;
        }
    }
}

// ---------------------------------------------------------------------------
// Kernel 2: fused masked multi-head glimpse attention via online softmax over
// 64-row tiles; epilogue computes glimpse and gl_proj. grid=256, 256 threads.
__global__ __launch_bounds__(256) void k_glimpse(
    const float* __restrict__ E, const float* __restrict__ Wn,
    const float* __restrict__ Wo,
    const int* __restrict__ maskI, const unsigned char* __restrict__ maskB,
    const int* __restrict__ flag,
    const float* __restrict__ qkp, float* __restrict__ glp)
{
    const int b = blockIdx.x;
    const int t = threadIdx.x;
    __shared__ float4 qk4[256];      // qkp, groups xor-swizzled g^(g>>3)
    __shared__ float4 Et[2048];      // E tile [64 rows][32 groups], swizzled g^(r&7)
    __shared__ float pc[64 * 33];    // partial compat [row][q*8+h], pad 33
    __shared__ float ct[64 * 9];     // compat [row][h], pad 9
    __shared__ float pt[64 * 8];     // p [row][h] (float4-readable)
    __shared__ float mh[8], lh[8], al[8];
    __shared__ float EbarF[8 * 128];
    __shared__ float heads[128];
    __shared__ float gl[128];

    const float4* E4 = (const float4*)(E + (size_t)b * 128000);
    const bool useB = (*flag != 0);

    {   // load + swizzle qkp
        const int h = t >> 5, g = t & 31;
        qk4[h * 32 + (g ^ (g >> 3))] = ((const float4*)(qkp + b * 1024))[t];
    }
    if (t < 8) { mh[t] = -3e38f; lh[t] = 0.f; }
    float4 eacc[8];
    #pragma unroll
    for (int h = 0; h < 8; ++h) eacc[h] = make_float4(0.f, 0.f, 0.f, 0.f);
    const int c4 = t & 31, sl = t >> 5;   // Ebar mapping
    const int rr = t >> 2, qq = t & 3;    // stage mapping: quarter-rows
    __syncthreads();

    for (int tile = 0; tile < 16; ++tile) {
        const int r0 = tile * 64;
        // ---- stage tile to LDS + partial compat in-registers ----
        {
            const int g = r0 + rr;
            float4 v[8];
            if (g < 1000) {
                #pragma unroll
                for (int i = 0; i < 8; ++i) v[i] = E4[g * 32 + qq * 8 + i];
            } else {
                #pragma unroll
                for (int i = 0; i < 8; ++i) v[i] = make_float4(0.f, 0.f, 0.f, 0.f);
            }
            float pch[8];
            #pragma unroll
            for (int h = 0; h < 8; ++h) pch[h] = 0.f;
            #pragma unroll
            for (int i = 0; i < 8; ++i) {
                const int grp = qq * 8 + i;
                Et[rr * 32 + (grp ^ (rr & 7))] = v[i];
                #pragma unroll
                for (int h = 0; h < 8; ++h) {
                    float4 w = qk4[h * 32 + (grp ^ qq)];
                    pch[h] += v[i].x * w.x + v[i].y * w.y + v[i].z * w.z + v[i].w * w.w;
                }
            }
            #pragma unroll
            for (int h = 0; h < 8; ++h) pc[rr * 33 + qq * 8 + h] = pch[h];
        }
        __syncthreads();
        // ---- reduce quarters, apply mask ----
        #pragma unroll
        for (int k = 0; k < 2; ++k) {
            const int idx = t + k * 256;
            const int row = idx >> 3, h = idx & 7;
            float s = pc[row * 33 + h] + pc[row * 33 + 8 + h]
                    + pc[row * 33 + 16 + h] + pc[row * 33 + 24 + h];
            const int g = r0 + row;
            const bool m = (g >= 1000) ||
                (useB ? (maskB[b * 1000 + g] != 0) : (maskI[b * 1000 + g] != 0));
            ct[row * 9 + h] = m ? NEG : s;
        }
        __syncthreads();
        // ---- per-head running max + rescale factor ----
        if (t < 8) {
            float mt = -3e38f;
            for (int r = 0; r < 64; ++r) mt = fmaxf(mt, ct[r * 9 + t]);
            const float mnew = fmaxf(mh[t], mt);
            al[t] = __expf(mh[t] - mnew);
            mh[t] = mnew;
        }
        __syncthreads();
        // ---- p = exp(compat - m) ----
        #pragma unroll
        for (int k = 0; k < 2; ++k) {
            const int idx = t + k * 256;
            const int row = idx >> 3, h = idx & 7;
            pt[row * 8 + h] = __expf(ct[row * 9 + h] - mh[h]);
        }
        __syncthreads();
        // ---- l update + Ebar accumulate (slice of 8 rows per thread) ----
        if (t < 8) {
            float s = 0.f;
            for (int r = 0; r < 64; ++r) s += pt[r * 8 + t];
            lh[t] = lh[t] * al[t] + s;
        }
        {
            #pragma unroll
            for (int h = 0; h < 8; ++h) {
                const float a = al[h];
                eacc[h].x *= a; eacc[h].y *= a; eacc[h].z *= a; eacc[h].w *= a;
            }
            #pragma unroll
            for (int j = 0; j < 8; ++j) {
                const int r = sl * 8 + j;
                const float4 ev = Et[r * 32 + (c4 ^ (r & 7))];
                const float4 p0 = ((float4*)pt)[r * 2];
                const float4 p1 = ((float4*)pt)[r * 2 + 1];
                eacc[0].x += p0.x * ev.x; eacc[0].y += p0.x * ev.y; eacc[0].z += p0.x * ev.z; eacc[0].w += p0.x * ev.w;
                eacc[1].x += p0.y * ev.x; eacc[1].y += p0.y * ev.y; eacc[1].z += p0.y * ev.z; eacc[1].w += p0.y * ev.w;
                eacc[2].x += p0.z * ev.x; eacc[2].y += p0.z * ev.y; eacc[2].z += p0.z * ev.z; eacc[2].w += p0.z * ev.w;
                eacc[3].x += p0.w * ev.x; eacc[3].y += p0.w * ev.y; eacc[3].z += p0.w * ev.z; eacc[3].w += p0.w * ev.w;
                eacc[4].x += p1.x * ev.x; eacc[4].y += p1.x * ev.y; eacc[4].z += p1.x * ev.z; eacc[4].w += p1.x * ev.w;
                eacc[5].x += p1.y * ev.x; eacc[5].y += p1.y * ev.y; eacc[5].z += p1.y * ev.z; eacc[5].w += p1.y * ev.w;
                eacc[6].x += p1.z * ev.x; eacc[6].y += p1.z * ev.y; eacc[6].z += p1.z * ev.z; eacc[6].w += p1.z * ev.w;
                eacc[7].x += p1.w * ev.x; eacc[7].y += p1.w * ev.y; eacc[7].z += p1.w * ev.z; eacc[7].w += p1.w * ev.w;
            }
        }
        __syncthreads();
    }

    // ---- reduce 8 slice-partials (reuse Et as scratch), fold 1/l ----
    #pragma unroll
    for (int h = 0; h < 8; ++h) Et[sl * 256 + h * 32 + c4] = eacc[h];
    __syncthreads();
    {
        const int h = t >> 5, cc = t & 31;
        float4 s = make_float4(0.f, 0.f, 0.f, 0.f);
        #pragma unroll
        for (int s2 = 0; s2 < 8; ++s2) {
            float4 v = Et[s2 * 256 + h * 32 + cc];
            s.x += v.x; s.y += v.y; s.z += v.z; s.w += v.w;
        }
        const float invl = 1.0f / lh[h];
        ((float4*)EbarF)[h * 32 + cc] =
            make_float4(s.x * invl, s.y * invl, s.z * invl, s.w * invl);
    }
    __syncthreads();
    // heads[j] = sum_c EbarF[h(j)][c] * Wn[c*384 + 128 + j]
    if (t < 128) {
        const int h = t >> 4;
        float acc = 0.f;
        for (int c = 0; c < 128; ++c) acc += EbarF[h * 128 + c] * Wn[c * 384 + 128 + t];
        heads[t] = acc;
    }
    __syncthreads();
    if (t < 128) {
        float acc = 0.f;
        for (int j2 = 0; j2 < 128; ++j2) acc += heads[j2] * Wo[j2 * 128 + t];
        gl[t] = acc;
    }
    __syncthreads();
    if (t < 128) {
        float acc = 0.f;
        for (int d2 = 0; d2 < 128; ++d2) acc += Wn[t * 384 + 256 + d2] * gl[d2];
        glp[b * 128 + t] = acc * 0.08838834764831845f; // 1/sqrt(128)
    }
}

// ---------------------------------------------------------------------------
// Kernel 3: logits = E@gl_proj, tanh clip, mask, log_softmax. grid=256.
__global__ __launch_bounds__(256) void k_logits(
    const float* __restrict__ E,
    const int* __restrict__ maskI, const unsigned char* __restrict__ maskB,
    const int* __restrict__ flag,
    const float* __restrict__ glp, float* __restrict__ out)
{
    const int b = blockIdx.x;
    const int t = threadIdx.x;
    __shared__ float gl[128];
    __shared__ float z[1024];
    __shared__ float pc[256];
    __shared__ float red[4];
    __shared__ float stat[2];

    const float4* E4 = (const float4*)(E + (size_t)b * 128000);
    const bool useB = (*flag != 0);
    if (t < 32) ((float4*)gl)[t] = ((const float4*)(glp + b * 128))[t];
    __syncthreads();

    const int rr = t >> 2, qq = t & 3;
    for (int tile = 0; tile < 16; ++tile) {
        const int g = tile * 64 + rr;
        float acc = 0.f;
        if (g < 1000) {
            #pragma unroll
            for (int i = 0; i < 8; ++i) {
                const float4 v = E4[g * 32 + qq * 8 + i];
                const float4 w = ((float4*)gl)[qq * 8 + i];
                acc += v.x * w.x + v.y * w.y + v.z * w.z + v.w * w.w;
            }
        }
        pc[t] = acc;
        __syncthreads();
        if (t < 64) {
            const int g2 = tile * 64 + t;
            if (g2 < 1000) {
                const float s = pc[t * 4] + pc[t * 4 + 1] + pc[t * 4 + 2] + pc[t * 4 + 3];
                float zz = 10.0f * tanhf(s);
                const bool m = useB ? (maskB[b * 1000 + g2] != 0)
                                    : (maskI[b * 1000 + g2] != 0);
                if (m) zz = NEG;
                z[g2] = zz;
            }
        }
        __syncthreads();
    }
    // block max
    float mloc = -3e38f;
    for (int idx = t; idx < 1000; idx += 256) mloc = fmaxf(mloc, z[idx]);
    #pragma unroll
    for (int off = 32; off > 0; off >>= 1) mloc = fmaxf(mloc, __shfl_down(mloc, off, 64));
    if ((t & 63) == 0) red[t >> 6] = mloc;
    __syncthreads();
    if (t == 0) stat[0] = fmaxf(fmaxf(red[0], red[1]), fmaxf(red[2], red[3]));
    __syncthreads();
    const float zmax = stat[0];
    float sloc = 0.f;
    for (int idx = t; idx < 1000; idx += 256) sloc += __expf(z[idx] - zmax);
    #pragma unroll
    for (int off = 32; off > 0; off >>= 1) sloc += __shfl_down(sloc, off, 64);
    if ((t & 63) == 0) red[t >> 6] = sloc;
    __syncthreads();
    if (t == 0) stat[1] = zmax + __logf(red[0] + red[1] + red[2] + red[3]);
    __syncthreads();
    const float lse = stat[1];
    for (int idx = t; idx < 1000; idx += 256)
        out[(size_t)b * 1000 + idx] = z[idx] - lse;
}

// ---------------------------------------------------------------------------
extern "C" void kernel_launch(void* const* d_in, const int* in_sizes, int n_in,
                              void* d_out, int out_size, void* d_ws, size_t ws_size,
                              hipStream_t stream) {
    const float* E  = (const float*)d_in[0];
    const float* Wn = (const float*)d_in[1];
    const float* Wf = (const float*)d_in[2];
    const float* Ws = (const float*)d_in[3];
    const float* Wo = (const float*)d_in[4];
    const int*   fi = (const int*)d_in[5];
    const int*   li = (const int*)d_in[6];
    const int*   maskI = (const int*)d_in[7];
    const unsigned char* maskB = (const unsigned char*)d_in[7];
    float* out = (float*)d_out;

    float* qkp = (float*)d_ws;                       // 256*1024 floats
    float* glp = qkp + 256 * 1024;                   // 256*128 floats
    int*   flag = (int*)(glp + 256 * 128);           // 1 int

    k_detect<<<1, 256, 0, stream>>>((const uint4*)d_in[7], flag);
    k_pre<<<256, 256, 0, stream>>>(E, Wn, Wf, Ws, fi, li, qkp);
    k_glimpse<<<256, 256, 0, stream>>>(E, Wn, Wo, maskI, maskB, flag, qkp, glp);
    k_logits<<<256, 256, 0, stream>>>(E, maskI, maskB, flag, glp, out);
}

// Round 3
// 335.223 us; speedup vs baseline: 2.4565x; 1.1909x over previous
//
#include <hip/hip_runtime.h>

// Problem: B=256, N=1000, D=128, H=8, dk=16
// out[b,n] = log_softmax over n of masked tanh-clipped pointer logits.
//
// Restructured math (removes the 393MB kvl intermediate):
//   qkp[b,h,c]  = 0.25 * sum_e W_node[c, h*16+e] * q[b, h*16+e]
//   compat[b,h,n] = sum_c E[b,n,c] * qkp[b,h,c]           (masked -> -1e9)
//   Ebar[b,h,c] = sum_n softmax_n(compat)[h,n] * E[b,n,c] (online softmax)
//   heads -> glimpse -> gl_proj[b,c] = (1/sqrt(128)) sum_d W_node[c,256+d]*glimpse[b,d]
//   logits[b,n] = sum_c E[b,n,c] * gl_proj[b,c]; z=10*tanh; mask; log_softmax.
//
// ws layout: qkp (256*1024 f32 = 1MB) | glp (256*128 f32 = 128KB) | mask flag (int)

#define NEG (-1e9f)

// ---------------------------------------------------------------------------
// Kernel 0: detect mask storage format (int32 vs byte upload). 16 KB scan.
__global__ void k_detect(const uint4* __restrict__ mw, int* __restrict__ flag)
{
    __shared__ int any_s;
    if (threadIdx.x == 0) any_s = 0;
    __syncthreads();
    unsigned acc = 0;
    #pragma unroll
    for (int i = 0; i < 4; ++i) {
        const uint4 v = mw[i * 256 + threadIdx.x];   // 16 KB total
        acc |= (v.x | v.y | v.z | v.w) & 0xFFFFFF00u;
    }
    if (acc) atomicOr(&any_s, 1);
    __syncthreads();
    if (threadIdx.x == 0) *flag = any_s;
}

// ---------------------------------------------------------------------------
// Kernel 1: per-b precompute: graph mean, q = fixed_ctx + step_ctx@W_step,
// then qkp[b,h,c]. grid=256 blocks.
// R2 fix: 256 threads (4 waves/CU, Occupancy 11.5%, 525 GB/s, 129 us) was
// latency-bound on the mean pass. Now 1024 threads (16 waves/CU): 32 row
// slices for the mean, 8-way-split q projection, 8 c-groups for qkp.
__global__ __launch_bounds__(1024) void k_pre(
    const float* __restrict__ E, const float* __restrict__ Wn,
    const float* __restrict__ Wf, const float* __restrict__ Ws,
    const int* __restrict__ fi, const int* __restrict__ li,
    float* __restrict__ qkp)
{
    const int b = blockIdx.x;
    const int t = threadIdx.x;
    __shared__ float4 red4[1024];            // 16 KB
    __shared__ float mu[128], e1[128], e2[128], q[128];
    __shared__ float qred[8][128];           // 4 KB

    const float4* E4 = (const float4*)(E + (size_t)b * 128000);

    // mean over n: thread (c4 = t&31, slice = t>>5), 32 slices of ~31 rows
    {
        const int c4 = t & 31, s = t >> 5;
        float4 acc = make_float4(0.f, 0.f, 0.f, 0.f);
        for (int r = s; r < 1000; r += 32) {
            float4 v = E4[r * 32 + c4];
            acc.x += v.x; acc.y += v.y; acc.z += v.z; acc.w += v.w;
        }
        red4[t] = acc;
    }
    // first/last node embeddings (independent of red4)
    if (t >= 512 && t < 544) {
        ((float4*)e1)[t - 512] = E4[fi[b] * 32 + (t - 512)];
    } else if (t >= 544 && t < 576) {
        ((float4*)e2)[t - 544] = E4[li[b] * 32 + (t - 544)];
    }
    __syncthreads();
    if (t < 32) {
        float4 acc = red4[t];
        #pragma unroll
        for (int s = 1; s < 32; ++s) {
            float4 v = red4[s * 32 + t];
            acc.x += v.x; acc.y += v.y; acc.z += v.z; acc.w += v.w;
        }
        const float inv = 1.0f / 1000.0f;
        ((float4*)mu)[t] = make_float4(acc.x * inv, acc.y * inv, acc.z * inv, acc.w * inv);
    }
    __syncthreads();
    // q[d] = sum_{k<384} src[k] * W[k][d], split 8 ways over k.
    // src = [mu | e1 | e2], W = [Wf ; Ws]  (Ws rows 0..255 cover k=128..383)
    {
        const int part = t >> 7, d = t & 127;      // wave-uniform part
        float acc = 0.f;
        const int k0 = part * 48;
        for (int k = k0; k < k0 + 48; ++k) {
            const float s = (k < 128) ? mu[k] : (k < 256 ? e1[k - 128] : e2[k - 256]);
            const float w = (k < 128) ? Wf[k * 128 + d] : Ws[(k - 128) * 128 + d];
            acc += s * w;
        }
        qred[part][d] = acc;
    }
    __syncthreads();
    if (t < 128) {
        float acc = 0.f;
        #pragma unroll
        for (int p = 0; p < 8; ++p) acc += qred[p][t];
        q[t] = acc;
    }
    __syncthreads();
    // qkp[h][c] = 0.25 * sum_e Wn[c*384 + h*16+e] * q[h*16+e]
    // lanes along j (coalesced Wn reads), 16-lane shuffle reduce per head.
    {
        const int j = t & 127, cg = t >> 7;
        const float qj = q[j];
        for (int c0 = 0; c0 < 128; c0 += 8) {
            const int c = c0 + cg;
            float v = Wn[c * 384 + j] * qj;
            v += __shfl_down(v, 8, 16);
            v += __shfl_down(v, 4, 16);
            v += __shfl_down(v, 2, 16);
            v += __shfl_down(v, 1, 16);
            if ((j & 15) == 0) qkp[b * 1024 + (j >> 4) * 128 + c] = v * 0.25f;
        }
    }
}

// ---------------------------------------------------------------------------
// Kernel 2: fused masked multi-head glimpse attention via online softmax over
// 64-row tiles; epilogue computes glimpse and gl_proj. grid=256, 256 threads.
__global__ __launch_bounds__(256) void k_glimpse(
    const float* __restrict__ E, const float* __restrict__ Wn,
    const float* __restrict__ Wo,
    const int* __restrict__ maskI, const unsigned char* __restrict__ maskB,
    const int* __restrict__ flag,
    const float* __restrict__ qkp, float* __restrict__ glp)
{
    const int b = blockIdx.x;
    const int t = threadIdx.x;
    __shared__ float4 qk4[256];      // qkp, groups xor-swizzled g^(g>>3)
    __shared__ float4 Et[2048];      // E tile [64 rows][32 groups], swizzled g^(r&7)
    __shared__ float pc[64 * 33];    // partial compat [row][q*8+h], pad 33
    __shared__ float ct[64 * 9];     // compat [row][h], pad 9
    __shared__ float pt[64 * 8];     // p [row][h] (float4-readable)
    __shared__ float mh[8], lh[8], al[8];
    __shared__ float EbarF[8 * 128];
    __shared__ float heads[128];
    __shared__ float gl[128];

    const float4* E4 = (const float4*)(E + (size_t)b * 128000);
    const bool useB = (*flag != 0);

    {   // load + swizzle qkp
        const int h = t >> 5, g = t & 31;
        qk4[h * 32 + (g ^ (g >> 3))] = ((const float4*)(qkp + b * 1024))[t];
    }
    if (t < 8) { mh[t] = -3e38f; lh[t] = 0.f; }
    float4 eacc[8];
    #pragma unroll
    for (int h = 0; h < 8; ++h) eacc[h] = make_float4(0.f, 0.f, 0.f, 0.f);
    const int c4 = t & 31, sl = t >> 5;   // Ebar mapping
    const int rr = t >> 2, qq = t & 3;    // stage mapping: quarter-rows
    __syncthreads();

    for (int tile = 0; tile < 16; ++tile) {
        const int r0 = tile * 64;
        // ---- stage tile to LDS + partial compat in-registers ----
        {
            const int g = r0 + rr;
            float4 v[8];
            if (g < 1000) {
                #pragma unroll
                for (int i = 0; i < 8; ++i) v[i] = E4[g * 32 + qq * 8 + i];
            } else {
                #pragma unroll
                for (int i = 0; i < 8; ++i) v[i] = make_float4(0.f, 0.f, 0.f, 0.f);
            }
            float pch[8];
            #pragma unroll
            for (int h = 0; h < 8; ++h) pch[h] = 0.f;
            #pragma unroll
            for (int i = 0; i < 8; ++i) {
                const int grp = qq * 8 + i;
                Et[rr * 32 + (grp ^ (rr & 7))] = v[i];
                #pragma unroll
                for (int h = 0; h < 8; ++h) {
                    float4 w = qk4[h * 32 + (grp ^ qq)];
                    pch[h] += v[i].x * w.x + v[i].y * w.y + v[i].z * w.z + v[i].w * w.w;
                }
            }
            #pragma unroll
            for (int h = 0; h < 8; ++h) pc[rr * 33 + qq * 8 + h] = pch[h];
        }
        __syncthreads();
        // ---- reduce quarters, apply mask ----
        #pragma unroll
        for (int k = 0; k < 2; ++k) {
            const int idx = t + k * 256;
            const int row = idx >> 3, h = idx & 7;
            float s = pc[row * 33 + h] + pc[row * 33 + 8 + h]
                    + pc[row * 33 + 16 + h] + pc[row * 33 + 24 + h];
            const int g = r0 + row;
            const bool m = (g >= 1000) ||
                (useB ? (maskB[b * 1000 + g] != 0) : (maskI[b * 1000 + g] != 0));
            ct[row * 9 + h] = m ? NEG : s;
        }
        __syncthreads();
        // ---- per-head running max + rescale factor ----
        if (t < 8) {
            float mt = -3e38f;
            for (int r = 0; r < 64; ++r) mt = fmaxf(mt, ct[r * 9 + t]);
            const float mnew = fmaxf(mh[t], mt);
            al[t] = __expf(mh[t] - mnew);
            mh[t] = mnew;
        }
        __syncthreads();
        // ---- p = exp(compat - m) ----
        #pragma unroll
        for (int k = 0; k < 2; ++k) {
            const int idx = t + k * 256;
            const int row = idx >> 3, h = idx & 7;
            pt[row * 8 + h] = __expf(ct[row * 9 + h] - mh[h]);
        }
        __syncthreads();
        // ---- l update + Ebar accumulate (slice of 8 rows per thread) ----
        if (t < 8) {
            float s = 0.f;
            for (int r = 0; r < 64; ++r) s += pt[r * 8 + t];
            lh[t] = lh[t] * al[t] + s;
        }
        {
            #pragma unroll
            for (int h = 0; h < 8; ++h) {
                const float a = al[h];
                eacc[h].x *= a; eacc[h].y *= a; eacc[h].z *= a; eacc[h].w *= a;
            }
            #pragma unroll
            for (int j = 0; j < 8; ++j) {
                const int r = sl * 8 + j;
                const float4 ev = Et[r * 32 + (c4 ^ (r & 7))];
                const float4 p0 = ((float4*)pt)[r * 2];
                const float4 p1 = ((float4*)pt)[r * 2 + 1];
                eacc[0].x += p0.x * ev.x; eacc[0].y += p0.x * ev.y; eacc[0].z += p0.x * ev.z; eacc[0].w += p0.x * ev.w;
                eacc[1].x += p0.y * ev.x; eacc[1].y += p0.y * ev.y; eacc[1].z += p0.y * ev.z; eacc[1].w += p0.y * ev.w;
                eacc[2].x += p0.z * ev.x; eacc[2].y += p0.z * ev.y; eacc[2].z += p0.z * ev.z; eacc[2].w += p0.z * ev.w;
                eacc[3].x += p0.w * ev.x; eacc[3].y += p0.w * ev.y; eacc[3].z += p0.w * ev.z; eacc[3].w += p0.w * ev.w;
                eacc[4].x += p1.x * ev.x; eacc[4].y += p1.x * ev.y; eacc[4].z += p1.x * ev.z; eacc[4].w += p1.x * ev.w;
                eacc[5].x += p1.y * ev.x; eacc[5].y += p1.y * ev.y; eacc[5].z += p1.y * ev.z; eacc[5].w += p1.y * ev.w;
                eacc[6].x += p1.z * ev.x; eacc[6].y += p1.z * ev.y; eacc[6].z += p1.z * ev.z; eacc[6].w += p1.z * ev.w;
                eacc[7].x += p1.w * ev.x; eacc[7].y += p1.w * ev.y; eacc[7].z += p1.w * ev.z; eacc[7].w += p1.w * ev.w;
            }
        }
        __syncthreads();
    }

    // ---- reduce 8 slice-partials (reuse Et as scratch), fold 1/l ----
    #pragma unroll
    for (int h = 0; h < 8; ++h) Et[sl * 256 + h * 32 + c4] = eacc[h];
    __syncthreads();
    {
        const int h = t >> 5, cc = t & 31;
        float4 s = make_float4(0.f, 0.f, 0.f, 0.f);
        #pragma unroll
        for (int s2 = 0; s2 < 8; ++s2) {
            float4 v = Et[s2 * 256 + h * 32 + cc];
            s.x += v.x; s.y += v.y; s.z += v.z; s.w += v.w;
        }
        const float invl = 1.0f / lh[h];
        ((float4*)EbarF)[h * 32 + cc] =
            make_float4(s.x * invl, s.y * invl, s.z * invl, s.w * invl);
    }
    __syncthreads();
    // heads[j] = sum_c EbarF[h(j)][c] * Wn[c*384 + 128 + j]
    if (t < 128) {
        const int h = t >> 4;
        float acc = 0.f;
        for (int c = 0; c < 128; ++c) acc += EbarF[h * 128 + c] * Wn[c * 384 + 128 + t];
        heads[t] = acc;
    }
    __syncthreads();
    if (t < 128) {
        float acc = 0.f;
        for (int j2 = 0; j2 < 128; ++j2) acc += heads[j2] * Wo[j2 * 128 + t];
        gl[t] = acc;
    }
    __syncthreads();
    if (t < 128) {
        float acc = 0.f;
        for (int d2 = 0; d2 < 128; ++d2) acc += Wn[t * 384 + 256 + d2] * gl[d2];
        glp[b * 128 + t] = acc * 0.08838834764831845f; // 1/sqrt(128)
    }
}

// ---------------------------------------------------------------------------
// Kernel 3: logits = E@gl_proj, tanh clip, mask, log_softmax. grid=256.
__global__ __launch_bounds__(256) void k_logits(
    const float* __restrict__ E,
    const int* __restrict__ maskI, const unsigned char* __restrict__ maskB,
    const int* __restrict__ flag,
    const float* __restrict__ glp, float* __restrict__ out)
{
    const int b = blockIdx.x;
    const int t = threadIdx.x;
    __shared__ float gl[128];
    __shared__ float z[1024];
    __shared__ float pc[256];
    __shared__ float red[4];
    __shared__ float stat[2];

    const float4* E4 = (const float4*)(E + (size_t)b * 128000);
    const bool useB = (*flag != 0);
    if (t < 32) ((float4*)gl)[t] = ((const float4*)(glp + b * 128))[t];
    __syncthreads();

    const int rr = t >> 2, qq = t & 3;
    for (int tile = 0; tile < 16; ++tile) {
        const int g = tile * 64 + rr;
        float acc = 0.f;
        if (g < 1000) {
            #pragma unroll
            for (int i = 0; i < 8; ++i) {
                const float4 v = E4[g * 32 + qq * 8 + i];
                const float4 w = ((float4*)gl)[qq * 8 + i];
                acc += v.x * w.x + v.y * w.y + v.z * w.z + v.w * w.w;
            }
        }
        pc[t] = acc;
        __syncthreads();
        if (t < 64) {
            const int g2 = tile * 64 + t;
            if (g2 < 1000) {
                const float s = pc[t * 4] + pc[t * 4 + 1] + pc[t * 4 + 2] + pc[t * 4 + 3];
                float zz = 10.0f * tanhf(s);
                const bool m = useB ? (maskB[b * 1000 + g2] != 0)
                                    : (maskI[b * 1000 + g2] != 0);
                if (m) zz = NEG;
                z[g2] = zz;
            }
        }
        __syncthreads();
    }
    // block max
    float mloc = -3e38f;
    for (int idx = t; idx < 1000; idx += 256) mloc = fmaxf(mloc, z[idx]);
    #pragma unroll
    for (int off = 32; off > 0; off >>= 1) mloc = fmaxf(mloc, __shfl_down(mloc, off, 64));
    if ((t & 63) == 0) red[t >> 6] = mloc;
    __syncthreads();
    if (t == 0) stat[0] = fmaxf(fmaxf(red[0], red[1]), fmaxf(red[2], red[3]));
    __syncthreads();
    const float zmax = stat[0];
    float sloc = 0.f;
    for (int idx = t; idx < 1000; idx += 256) sloc += __expf(z[idx] - zmax);
    #pragma unroll
    for (int off = 32; off > 0; off >>= 1) sloc += __shfl_down(sloc, off, 64);
    if ((t & 63) == 0) red[t >> 6] = sloc;
    __syncthreads();
    if (t == 0) stat[1] = zmax + __logf(red[0] + red[1] + red[2] + red[3]);
    __syncthreads();
    const float lse = stat[1];
    for (int idx = t; idx < 1000; idx += 256)
        out[(size_t)b * 1000 + idx] = z[idx] - lse;
}

// ---------------------------------------------------------------------------
extern "C" void kernel_launch(void* const* d_in, const int* in_sizes, int n_in,
                              void* d_out, int out_size, void* d_ws, size_t ws_size,
                              hipStream_t stream) {
    const float* E  = (const float*)d_in[0];
    const float* Wn = (const float*)d_in[1];
    const float* Wf = (const float*)d_in[2];
    const float* Ws = (const float*)d_in[3];
    const float* Wo = (const float*)d_in[4];
    const int*   fi = (const int*)d_in[5];
    const int*   li = (const int*)d_in[6];
    const int*   maskI = (const int*)d_in[7];
    const unsigned char* maskB = (const unsigned char*)d_in[7];
    float* out = (float*)d_out;

    float* qkp = (float*)d_ws;                       // 256*1024 floats
    float* glp = qkp + 256 * 1024;                   // 256*128 floats
    int*   flag = (int*)(glp + 256 * 128);           // 1 int

    k_detect<<<1, 256, 0, stream>>>((const uint4*)d_in[7], flag);
    k_pre<<<256, 1024, 0, stream>>>(E, Wn, Wf, Ws, fi, li, qkp);
    k_glimpse<<<256, 256, 0, stream>>>(E, Wn, Wo, maskI, maskB, flag, qkp, glp);
    k_logits<<<256, 256, 0, stream>>>(E, maskI, maskB, flag, glp, out);
}

// Round 4
// 299.570 us; speedup vs baseline: 2.7489x; 1.1190x over previous
//
#include <hip/hip_runtime.h>

// Problem: B=256, N=1000, D=128, H=8, dk=16
// out[b,n] = log_softmax over n of masked tanh-clipped pointer logits.
//
// Restructured math (removes the 393MB kvl intermediate):
//   qkp[b,h,c]  = 0.25 * sum_e W_node[c, h*16+e] * q[b, h*16+e]
//   compat[b,h,n] = sum_c E[b,n,c] * qkp[b,h,c]           (masked -> -1e9)
//   Ebar[b,h,c] = sum_n softmax_n(compat)[h,n] * E[b,n,c] (online softmax)
//   heads -> glimpse -> gl_proj[b,c] = (1/sqrt(128)) sum_d W_node[c,256+d]*glimpse[b,d]
//   logits[b,n] = sum_c E[b,n,c] * gl_proj[b,c]; z=10*tanh; mask; log_softmax.
//
// ws layout: qkp (256*1024 f32 = 1MB) | glp (256*128 f32 = 128KB) | mask flag (int)

#define NEG (-1e9f)

// ---------------------------------------------------------------------------
// Kernel 0: detect mask storage format (int32 vs byte upload). 16 KB scan.
__global__ void k_detect(const uint4* __restrict__ mw, int* __restrict__ flag)
{
    __shared__ int any_s;
    if (threadIdx.x == 0) any_s = 0;
    __syncthreads();
    unsigned acc = 0;
    #pragma unroll
    for (int i = 0; i < 4; ++i) {
        const uint4 v = mw[i * 256 + threadIdx.x];   // 16 KB total
        acc |= (v.x | v.y | v.z | v.w) & 0xFFFFFF00u;
    }
    if (acc) atomicOr(&any_s, 1);
    __syncthreads();
    if (threadIdx.x == 0) *flag = any_s;
}

// ---------------------------------------------------------------------------
// Kernel 1: per-b precompute: graph mean, q = fixed_ctx + step_ctx@W_step,
// then qkp[b,h,c]. grid=256 blocks, 1024 threads (R3: 16 waves/CU).
__global__ __launch_bounds__(1024) void k_pre(
    const float* __restrict__ E, const float* __restrict__ Wn,
    const float* __restrict__ Wf, const float* __restrict__ Ws,
    const int* __restrict__ fi, const int* __restrict__ li,
    float* __restrict__ qkp)
{
    const int b = blockIdx.x;
    const int t = threadIdx.x;
    __shared__ float4 red4[1024];            // 16 KB
    __shared__ float mu[128], e1[128], e2[128], q[128];
    __shared__ float qred[8][128];           // 4 KB

    const float4* E4 = (const float4*)(E + (size_t)b * 128000);

    // mean over n: thread (c4 = t&31, slice = t>>5), 32 slices of ~31 rows
    {
        const int c4 = t & 31, s = t >> 5;
        float4 acc = make_float4(0.f, 0.f, 0.f, 0.f);
        for (int r = s; r < 1000; r += 32) {
            float4 v = E4[r * 32 + c4];
            acc.x += v.x; acc.y += v.y; acc.z += v.z; acc.w += v.w;
        }
        red4[t] = acc;
    }
    // first/last node embeddings (independent of red4)
    if (t >= 512 && t < 544) {
        ((float4*)e1)[t - 512] = E4[fi[b] * 32 + (t - 512)];
    } else if (t >= 544 && t < 576) {
        ((float4*)e2)[t - 544] = E4[li[b] * 32 + (t - 544)];
    }
    __syncthreads();
    if (t < 32) {
        float4 acc = red4[t];
        #pragma unroll
        for (int s = 1; s < 32; ++s) {
            float4 v = red4[s * 32 + t];
            acc.x += v.x; acc.y += v.y; acc.z += v.z; acc.w += v.w;
        }
        const float inv = 1.0f / 1000.0f;
        ((float4*)mu)[t] = make_float4(acc.x * inv, acc.y * inv, acc.z * inv, acc.w * inv);
    }
    __syncthreads();
    // q[d] = sum_{k<384} src[k] * W[k][d], split 8 ways over k.
    {
        const int part = t >> 7, d = t & 127;      // wave-uniform part
        float acc = 0.f;
        const int k0 = part * 48;
        for (int k = k0; k < k0 + 48; ++k) {
            const float s = (k < 128) ? mu[k] : (k < 256 ? e1[k - 128] : e2[k - 256]);
            const float w = (k < 128) ? Wf[k * 128 + d] : Ws[(k - 128) * 128 + d];
            acc += s * w;
        }
        qred[part][d] = acc;
    }
    __syncthreads();
    if (t < 128) {
        float acc = 0.f;
        #pragma unroll
        for (int p = 0; p < 8; ++p) acc += qred[p][t];
        q[t] = acc;
    }
    __syncthreads();
    // qkp[h][c] = 0.25 * sum_e Wn[c*384 + h*16+e] * q[h*16+e]
    {
        const int j = t & 127, cg = t >> 7;
        const float qj = q[j];
        for (int c0 = 0; c0 < 128; c0 += 8) {
            const int c = c0 + cg;
            float v = Wn[c * 384 + j] * qj;
            v += __shfl_down(v, 8, 16);
            v += __shfl_down(v, 4, 16);
            v += __shfl_down(v, 2, 16);
            v += __shfl_down(v, 1, 16);
            if ((j & 15) == 0) qkp[b * 1024 + (j >> 4) * 128 + c] = v * 0.25f;
        }
    }
}

// ---------------------------------------------------------------------------
// Kernel 2: fused masked multi-head glimpse attention via online softmax.
// R4: 512 threads, 128-row tiles (was 256 threads / 64-row tiles at 10.8%
// occupancy, 723 GB/s, latency-bound). pc re-padded 33->36/9 to kill the
// 8-way quarter-reduce bank conflict. grid=256, 512 threads.
__global__ __launch_bounds__(512) void k_glimpse(
    const float* __restrict__ E, const float* __restrict__ Wn,
    const float* __restrict__ Wo,
    const int* __restrict__ maskI, const unsigned char* __restrict__ maskB,
    const int* __restrict__ flag,
    const float* __restrict__ qkp, float* __restrict__ glp)
{
    const int b = blockIdx.x;
    const int t = threadIdx.x;
    __shared__ float4 qk4[256];      // qkp, groups xor-swizzled g^(g>>3)  (4 KB)
    __shared__ float4 Et[4096];      // E tile [128 rows][32 groups], swizzled g^(r&7) (64 KB)
    __shared__ float pc[128 * 36];   // partial compat [row][q*9+h]  (18.4 KB)
    __shared__ float ct[128 * 9];    // compat [row][h], pad 9  (4.6 KB)
    __shared__ float pt[128 * 8];    // p [row][h] (float4-readable)  (4 KB)
    __shared__ float redh[8 * 9];    // [part][h] two-stage head reductions
    __shared__ float mh[8], lh[8], al[8];
    __shared__ float EbarF[8 * 128];
    __shared__ float heads[128];
    __shared__ float gl[128];

    const float4* E4 = (const float4*)(E + (size_t)b * 128000);
    const bool useB = (*flag != 0);

    if (t < 256) {   // load + swizzle qkp
        const int h = t >> 5, g = t & 31;
        qk4[h * 32 + (g ^ (g >> 3))] = ((const float4*)(qkp + b * 1024))[t];
    }
    if (t < 8) { mh[t] = -3e38f; lh[t] = 0.f; }
    float4 eacc[8];
    #pragma unroll
    for (int h = 0; h < 8; ++h) eacc[h] = make_float4(0.f, 0.f, 0.f, 0.f);
    const int c4 = t & 31, sl = t >> 5;   // Ebar mapping: sl in [0,16), 8 rows each
    const int rr = t >> 2, qq = t & 3;    // stage mapping: rr in [0,128)
    __syncthreads();

    for (int tile = 0; tile < 8; ++tile) {
        const int r0 = tile * 128;
        // ---- stage tile to LDS + partial compat in-registers ----
        {
            const int g = r0 + rr;
            float4 v[8];
            if (g < 1000) {
                #pragma unroll
                for (int i = 0; i < 8; ++i) v[i] = E4[g * 32 + qq * 8 + i];
            } else {
                #pragma unroll
                for (int i = 0; i < 8; ++i) v[i] = make_float4(0.f, 0.f, 0.f, 0.f);
            }
            float pch[8];
            #pragma unroll
            for (int h = 0; h < 8; ++h) pch[h] = 0.f;
            #pragma unroll
            for (int i = 0; i < 8; ++i) {
                const int grp = qq * 8 + i;
                Et[rr * 32 + (grp ^ (rr & 7))] = v[i];
                #pragma unroll
                for (int h = 0; h < 8; ++h) {
                    float4 w = qk4[h * 32 + (grp ^ qq)];
                    pch[h] += v[i].x * w.x + v[i].y * w.y + v[i].z * w.z + v[i].w * w.w;
                }
            }
            #pragma unroll
            for (int h = 0; h < 8; ++h) pc[rr * 36 + qq * 9 + h] = pch[h];
        }
        __syncthreads();
        // ---- reduce quarters, apply mask (1024 outputs, 512 threads) ----
        #pragma unroll
        for (int k = 0; k < 2; ++k) {
            const int idx = t + k * 512;
            const int row = idx >> 3, h = idx & 7;
            float s = pc[row * 36 + h] + pc[row * 36 + 9 + h]
                    + pc[row * 36 + 18 + h] + pc[row * 36 + 27 + h];
            const int g = r0 + row;
            const bool m = (g >= 1000) ||
                (useB ? (maskB[b * 1000 + g] != 0) : (maskI[b * 1000 + g] != 0));
            ct[row * 9 + h] = m ? NEG : s;
        }
        __syncthreads();
        // ---- per-head running max, two-stage ----
        if (t < 64) {
            const int h = t & 7, part = t >> 3;
            float mt = -3e38f;
            const int rb = part * 16;
            for (int r = 0; r < 16; ++r) mt = fmaxf(mt, ct[(rb + r) * 9 + h]);
            redh[part * 9 + h] = mt;
        }
        __syncthreads();
        if (t < 8) {
            float mt = redh[t];
            for (int p = 1; p < 8; ++p) mt = fmaxf(mt, redh[p * 9 + t]);
            const float mnew = fmaxf(mh[t], mt);
            al[t] = __expf(mh[t] - mnew);
            mh[t] = mnew;
        }
        __syncthreads();
        // ---- p = exp(compat - m) ----
        #pragma unroll
        for (int k = 0; k < 2; ++k) {
            const int idx = t + k * 512;
            const int row = idx >> 3, h = idx & 7;
            pt[row * 8 + h] = __expf(ct[row * 9 + h] - mh[h]);
        }
        __syncthreads();
        // ---- Ebar accumulate (slice of 8 rows per thread) + l partials ----
        {
            #pragma unroll
            for (int h = 0; h < 8; ++h) {
                const float a = al[h];
                eacc[h].x *= a; eacc[h].y *= a; eacc[h].z *= a; eacc[h].w *= a;
            }
            #pragma unroll
            for (int j = 0; j < 8; ++j) {
                const int r = sl * 8 + j;
                const float4 ev = Et[r * 32 + (c4 ^ (r & 7))];
                const float4 p0 = ((float4*)pt)[r * 2];
                const float4 p1 = ((float4*)pt)[r * 2 + 1];
                eacc[0].x += p0.x * ev.x; eacc[0].y += p0.x * ev.y; eacc[0].z += p0.x * ev.z; eacc[0].w += p0.x * ev.w;
                eacc[1].x += p0.y * ev.x; eacc[1].y += p0.y * ev.y; eacc[1].z += p0.y * ev.z; eacc[1].w += p0.y * ev.w;
                eacc[2].x += p0.z * ev.x; eacc[2].y += p0.z * ev.y; eacc[2].z += p0.z * ev.z; eacc[2].w += p0.z * ev.w;
                eacc[3].x += p0.w * ev.x; eacc[3].y += p0.w * ev.y; eacc[3].z += p0.w * ev.z; eacc[3].w += p0.w * ev.w;
                eacc[4].x += p1.x * ev.x; eacc[4].y += p1.x * ev.y; eacc[4].z += p1.x * ev.z; eacc[4].w += p1.x * ev.w;
                eacc[5].x += p1.y * ev.x; eacc[5].y += p1.y * ev.y; eacc[5].z += p1.y * ev.z; eacc[5].w += p1.y * ev.w;
                eacc[6].x += p1.z * ev.x; eacc[6].y += p1.z * ev.y; eacc[6].z += p1.z * ev.z; eacc[6].w += p1.z * ev.w;
                eacc[7].x += p1.w * ev.x; eacc[7].y += p1.w * ev.y; eacc[7].z += p1.w * ev.z; eacc[7].w += p1.w * ev.w;
            }
        }
        if (t < 64) {
            const int h = t & 7, part = t >> 3;
            float s = 0.f;
            const int rb = part * 16;
            for (int r = 0; r < 16; ++r) s += pt[(rb + r) * 8 + h];
            redh[part * 9 + h] = s;
        }
        __syncthreads();
        // lh update after barrier: safe — next write to redh/al is >=2 barriers away,
        // and all t<8 must pass the next barriers before anyone can overwrite.
        if (t < 8) {
            float s = 0.f;
            for (int p = 0; p < 8; ++p) s += redh[p * 9 + t];
            lh[t] = lh[t] * al[t] + s;
        }
    }

    // ---- reduce 16 slice-partials (reuse Et as scratch: 16*256=4096), fold 1/l ----
    #pragma unroll
    for (int h = 0; h < 8; ++h) Et[sl * 256 + h * 32 + c4] = eacc[h];
    __syncthreads();
    if (t < 256) {
        const int h = t >> 5, cc = t & 31;
        float4 s = make_float4(0.f, 0.f, 0.f, 0.f);
        #pragma unroll
        for (int s2 = 0; s2 < 16; ++s2) {
            float4 v = Et[s2 * 256 + h * 32 + cc];
            s.x += v.x; s.y += v.y; s.z += v.z; s.w += v.w;
        }
        const float invl = 1.0f / lh[h];
        ((float4*)EbarF)[h * 32 + cc] =
            make_float4(s.x * invl, s.y * invl, s.z * invl, s.w * invl);
    }
    __syncthreads();
    // heads[j] = sum_c EbarF[h(j)][c] * Wn[c*384 + 128 + j]
    if (t < 128) {
        const int h = t >> 4;
        float acc = 0.f;
        for (int c = 0; c < 128; ++c) acc += EbarF[h * 128 + c] * Wn[c * 384 + 128 + t];
        heads[t] = acc;
    }
    __syncthreads();
    if (t < 128) {
        float acc = 0.f;
        for (int j2 = 0; j2 < 128; ++j2) acc += heads[j2] * Wo[j2 * 128 + t];
        gl[t] = acc;
    }
    __syncthreads();
    if (t < 128) {
        float acc = 0.f;
        for (int d2 = 0; d2 < 128; ++d2) acc += Wn[t * 384 + 256 + d2] * gl[d2];
        glp[b * 128 + t] = acc * 0.08838834764831845f; // 1/sqrt(128)
    }
}

// ---------------------------------------------------------------------------
// Kernel 3: logits = E@gl_proj, tanh clip, mask, log_softmax.
// R4: 1024 threads (16 waves/CU), 128-row tiles, one element/thread softmax.
__global__ __launch_bounds__(1024) void k_logits(
    const float* __restrict__ E,
    const int* __restrict__ maskI, const unsigned char* __restrict__ maskB,
    const int* __restrict__ flag,
    const float* __restrict__ glp, float* __restrict__ out)
{
    const int b = blockIdx.x;
    const int t = threadIdx.x;
    __shared__ float gl[128];
    __shared__ float z[1024];
    __shared__ float pc[128 * 9];
    __shared__ float red[16];
    __shared__ float stat[2];

    const float4* E4 = (const float4*)(E + (size_t)b * 128000);
    const bool useB = (*flag != 0);
    if (t < 32) ((float4*)gl)[t] = ((const float4*)(glp + b * 128))[t];
    __syncthreads();

    const int row = t >> 3, sub = t & 7;   // 128 rows x 8 channel-subs of 16
    for (int tile = 0; tile < 8; ++tile) {
        const int g = tile * 128 + row;
        float acc = 0.f;
        if (g < 1000) {
            #pragma unroll
            for (int i = 0; i < 4; ++i) {
                const float4 v = E4[g * 32 + sub * 4 + i];
                const float4 w = ((float4*)gl)[sub * 4 + i];
                acc += v.x * w.x + v.y * w.y + v.z * w.z + v.w * w.w;
            }
        }
        pc[row * 9 + sub] = acc;
        __syncthreads();
        if (t < 128) {
            const int g2 = tile * 128 + t;
            if (g2 < 1000) {
                float s = 0.f;
                #pragma unroll
                for (int q2 = 0; q2 < 8; ++q2) s += pc[t * 9 + q2];
                float zz = 10.0f * tanhf(s);
                const bool m = useB ? (maskB[b * 1000 + g2] != 0)
                                    : (maskI[b * 1000 + g2] != 0);
                if (m) zz = NEG;
                z[g2] = zz;
            }
        }
        __syncthreads();
    }
    // block max (one element per thread)
    float v = (t < 1000) ? z[t] : -3e38f;
    #pragma unroll
    for (int off = 32; off > 0; off >>= 1) v = fmaxf(v, __shfl_down(v, off, 64));
    if ((t & 63) == 0) red[t >> 6] = v;
    __syncthreads();
    if (t == 0) {
        float m = red[0];
        for (int i = 1; i < 16; ++i) m = fmaxf(m, red[i]);
        stat[0] = m;
    }
    __syncthreads();
    const float zmax = stat[0];
    float sv = (t < 1000) ? __expf(z[t] - zmax) : 0.f;
    #pragma unroll
    for (int off = 32; off > 0; off >>= 1) sv += __shfl_down(sv, off, 64);
    if ((t & 63) == 0) red[t >> 6] = sv;
    __syncthreads();
    if (t == 0) {
        float s = 0.f;
        for (int i = 0; i < 16; ++i) s += red[i];
        stat[1] = zmax + __logf(s);
    }
    __syncthreads();
    if (t < 1000)
        out[(size_t)b * 1000 + t] = z[t] - stat[1];
}

// ---------------------------------------------------------------------------
extern "C" void kernel_launch(void* const* d_in, const int* in_sizes, int n_in,
                              void* d_out, int out_size, void* d_ws, size_t ws_size,
                              hipStream_t stream) {
    const float* E  = (const float*)d_in[0];
    const float* Wn = (const float*)d_in[1];
    const float* Wf = (const float*)d_in[2];
    const float* Ws = (const float*)d_in[3];
    const float* Wo = (const float*)d_in[4];
    const int*   fi = (const int*)d_in[5];
    const int*   li = (const int*)d_in[6];
    const int*   maskI = (const int*)d_in[7];
    const unsigned char* maskB = (const unsigned char*)d_in[7];
    float* out = (float*)d_out;

    float* qkp = (float*)d_ws;                       // 256*1024 floats
    float* glp = qkp + 256 * 1024;                   // 256*128 floats
    int*   flag = (int*)(glp + 256 * 128);           // 1 int

    k_detect<<<1, 256, 0, stream>>>((const uint4*)d_in[7], flag);
    k_pre<<<256, 1024, 0, stream>>>(E, Wn, Wf, Ws, fi, li, qkp);
    k_glimpse<<<256, 512, 0, stream>>>(E, Wn, Wo, maskI, maskB, flag, qkp, glp);
    k_logits<<<256, 1024, 0, stream>>>(E, maskI, maskB, flag, glp, out);
}

// Round 5
// 281.830 us; speedup vs baseline: 2.9219x; 1.0629x over previous
//
#include <hip/hip_runtime.h>

// Problem: B=256, N=1000, D=128, H=8, dk=16. grid=256 (one block per b) —
// exactly 1 block/CU, so occupancy == waves-per-block. R5: single fused
// 1024-thread kernel (16 waves/CU) replacing 4 launches; qkp/glp live in LDS.
//
// Math (removes the 393MB kvl intermediate):
//   qkp[h,c]  = 0.25 * sum_e W_node[c, h*16+e] * q[h*16+e]
//   compat[h,n] = sum_c E[n,c] * qkp[h,c]            (masked -> -1e9)
//   Ebar[h,c] = sum_n softmax_n(compat)[h,n] * E[n,c] (online softmax)
//   heads -> glimpse -> gp[c] = (1/sqrt(128)) sum_d W_node[c,256+d]*glimpse[d]
//   logits[n] = sum_c E[n,c] * gp[c]; z=10*tanh; mask; log_softmax.

#define NEG (-1e9f)

__global__ __launch_bounds__(1024) void k_fused(
    const float* __restrict__ E, const float* __restrict__ Wn,
    const float* __restrict__ Wf, const float* __restrict__ Ws,
    const float* __restrict__ Wo,
    const int* __restrict__ fi, const int* __restrict__ li,
    const int* __restrict__ maskI, const unsigned char* __restrict__ maskB,
    float* __restrict__ out)
{
    const int b = blockIdx.x;
    const int t = threadIdx.x;

    __shared__ float4 Et[4096];      // 64 KB: mean scratch / E tile / Ebar reduce
    __shared__ float4 qk4[256];      // qkp, float4-slot swizzle s^(s>>2)
    __shared__ float4 pt4[256];      // p [row][h] in phase C; z[] in phase E
    __shared__ float4 EbarF4[256];
    __shared__ float4 mu4[32], e14[32], e24[32], gp4[32];
    __shared__ float q[128], heads[128], gl[128];
    __shared__ float qred[8][128];
    __shared__ float ct[128 * 9];    // compat [row][h] pad 9; logit partials in E
    __shared__ float redh[72];
    __shared__ float mh[8], lh[8], al[8];
    __shared__ float red[16];
    __shared__ float stat[2];
    __shared__ int flagS;

    float* const mu = (float*)mu4;
    float* const e1 = (float*)e14;
    float* const e2 = (float*)e24;
    float* const gp = (float*)gp4;
    float* const pt = (float*)pt4;
    float* const EbarF = (float*)EbarF4;
    float* const qkf = (float*)qk4;

    const float4* E4 = (const float4*)(E + (size_t)b * 128000);

    if (t == 0) flagS = 0;
    // mask-format probe: int32 upload => every word 0/1 => upper 3 bytes zero.
    // Byte upload => ~50% nonzero upper bytes over 16 KB. (OR deferred past
    // barrier #1 so the flagS init is safe.)
    const uint4 dv = ((const uint4*)maskI)[t];           // first 16 KB
    const unsigned det = (dv.x | dv.y | dv.z | dv.w) & 0xFFFFFF00u;

    // ---- Phase A: graph mean (red4 := Et), first/last embeddings ----
    {
        const int cm = t & 31, sm = t >> 5;
        float4 acc = make_float4(0.f, 0.f, 0.f, 0.f);
        for (int r = sm; r < 1000; r += 32) {
            const float4 v = E4[r * 32 + cm];
            acc.x += v.x; acc.y += v.y; acc.z += v.z; acc.w += v.w;
        }
        Et[t] = acc;
    }
    if (t >= 512 && t < 544) {
        e14[t - 512] = E4[fi[b] * 32 + (t - 512)];
    } else if (t >= 544 && t < 576) {
        e24[t - 544] = E4[li[b] * 32 + (t - 544)];
    }
    __syncthreads();
    if (det) atomicOr(&flagS, 1);
    if (t < 32) {
        float4 acc = Et[t];
        #pragma unroll
        for (int s = 1; s < 32; ++s) {
            const float4 v = Et[s * 32 + t];
            acc.x += v.x; acc.y += v.y; acc.z += v.z; acc.w += v.w;
        }
        const float inv = 1.0f / 1000.0f;
        mu4[t] = make_float4(acc.x * inv, acc.y * inv, acc.z * inv, acc.w * inv);
    }
    __syncthreads();

    // ---- Phase B: q = mu@Wf + e1@Ws[0:128] + e2@Ws[128:256], 8-way k-split ----
    {
        const int part = t >> 7, d = t & 127;
        float acc = 0.f;
        const int k0 = part * 48;
        for (int k = k0; k < k0 + 48; ++k) {
            const float s = (k < 128) ? mu[k] : (k < 256 ? e1[k - 128] : e2[k - 256]);
            const float w = (k < 128) ? Wf[k * 128 + d] : Ws[(k - 128) * 128 + d];
            acc += s * w;
        }
        qred[part][d] = acc;
    }
    __syncthreads();
    if (t < 128) {
        float acc = 0.f;
        #pragma unroll
        for (int p = 0; p < 8; ++p) acc += qred[p][t];
        q[t] = acc;
    }
    __syncthreads();
    // qkp[h][c] -> qk4 (LDS only). j lanes over the 128-dim, 16-lane reduce/head.
    {
        const int j = t & 127, cg = t >> 7;
        const float qj = q[j];
        for (int c0 = 0; c0 < 128; c0 += 8) {
            const int c = c0 + cg;
            float v = Wn[c * 384 + j] * qj;
            v += __shfl_down(v, 8, 16);
            v += __shfl_down(v, 4, 16);
            v += __shfl_down(v, 2, 16);
            v += __shfl_down(v, 1, 16);
            if ((j & 15) == 0) {
                const int h = j >> 4, s = c >> 2;
                qkf[h * 128 + (s ^ (s >> 2)) * 4 + (c & 3)] = v * 0.25f;
            }
        }
    }
    __syncthreads();

    const bool useB = (flagS != 0);

    // ---- Phase C: online-softmax glimpse attention, 8 tiles x 128 rows ----
    if (t < 8) { mh[t] = -3e38f; lh[t] = 0.f; }
    float4 eacc[8];
    #pragma unroll
    for (int h = 0; h < 8; ++h) eacc[h] = make_float4(0.f, 0.f, 0.f, 0.f);
    const int c4 = t & 31, sl = t >> 5;   // Ebar: 32 slices x 4 rows
    const int rr = t >> 3, qq = t & 7;    // stage: 128 rows x 8 octants

    for (int tile = 0; tile < 8; ++tile) {
        const int r0 = tile * 128;
        // stage tile to LDS + compat partials + 8-lane butterfly reduce
        {
            const int g = r0 + rr;
            float4 v[4];
            if (g < 1000) {
                #pragma unroll
                for (int i = 0; i < 4; ++i) v[i] = E4[g * 32 + qq * 4 + i];
            } else {
                #pragma unroll
                for (int i = 0; i < 4; ++i) v[i] = make_float4(0.f, 0.f, 0.f, 0.f);
            }
            float pch[8];
            #pragma unroll
            for (int h = 0; h < 8; ++h) pch[h] = 0.f;
            #pragma unroll
            for (int i = 0; i < 4; ++i) {
                const int grp = qq * 4 + i;
                Et[rr * 32 + (grp ^ (rr & 7))] = v[i];
                const int sg = grp ^ (grp >> 2);
                #pragma unroll
                for (int h = 0; h < 8; ++h) {
                    const float4 w = qk4[h * 32 + sg];
                    pch[h] += v[i].x * w.x + v[i].y * w.y + v[i].z * w.z + v[i].w * w.w;
                }
            }
            #pragma unroll
            for (int m = 1; m <= 4; m <<= 1) {
                #pragma unroll
                for (int h = 0; h < 8; ++h) pch[h] += __shfl_xor(pch[h], m, 64);
            }
            bool msk = (g >= 1000);
            if (!msk) msk = useB ? (maskB[b * 1000 + g] != 0)
                                 : (maskI[b * 1000 + g] != 0);
            ct[rr * 9 + qq] = msk ? NEG : pch[qq];
        }
        __syncthreads();
        // running max, two-stage
        if (t < 64) {
            const int h = t & 7, part = t >> 3;
            float mt = -3e38f;
            const int rb = part * 16;
            for (int r = 0; r < 16; ++r) mt = fmaxf(mt, ct[(rb + r) * 9 + h]);
            redh[part * 9 + h] = mt;
        }
        __syncthreads();
        if (t < 8) {
            float mt = redh[t];
            for (int p = 1; p < 8; ++p) mt = fmaxf(mt, redh[p * 9 + t]);
            const float mnew = fmaxf(mh[t], mt);
            al[t] = __expf(mh[t] - mnew);
            mh[t] = mnew;
        }
        __syncthreads();
        // p = exp(compat - m), one element per thread
        {
            const int row = t >> 3, h = t & 7;
            pt[row * 8 + h] = __expf(ct[row * 9 + h] - mh[h]);
        }
        __syncthreads();
        // Ebar accumulate (4 rows/thread) + l partials
        {
            #pragma unroll
            for (int h = 0; h < 8; ++h) {
                const float a = al[h];
                eacc[h].x *= a; eacc[h].y *= a; eacc[h].z *= a; eacc[h].w *= a;
            }
            #pragma unroll
            for (int j = 0; j < 4; ++j) {
                const int r = sl * 4 + j;
                const float4 ev = Et[r * 32 + (c4 ^ (r & 7))];
                const float4 p0 = pt4[r * 2];
                const float4 p1 = pt4[r * 2 + 1];
                eacc[0].x += p0.x * ev.x; eacc[0].y += p0.x * ev.y; eacc[0].z += p0.x * ev.z; eacc[0].w += p0.x * ev.w;
                eacc[1].x += p0.y * ev.x; eacc[1].y += p0.y * ev.y; eacc[1].z += p0.y * ev.z; eacc[1].w += p0.y * ev.w;
                eacc[2].x += p0.z * ev.x; eacc[2].y += p0.z * ev.y; eacc[2].z += p0.z * ev.z; eacc[2].w += p0.z * ev.w;
                eacc[3].x += p0.w * ev.x; eacc[3].y += p0.w * ev.y; eacc[3].z += p0.w * ev.z; eacc[3].w += p0.w * ev.w;
                eacc[4].x += p1.x * ev.x; eacc[4].y += p1.x * ev.y; eacc[4].z += p1.x * ev.z; eacc[4].w += p1.x * ev.w;
                eacc[5].x += p1.y * ev.x; eacc[5].y += p1.y * ev.y; eacc[5].z += p1.y * ev.z; eacc[5].w += p1.y * ev.w;
                eacc[6].x += p1.z * ev.x; eacc[6].y += p1.z * ev.y; eacc[6].z += p1.z * ev.z; eacc[6].w += p1.z * ev.w;
                eacc[7].x += p1.w * ev.x; eacc[7].y += p1.w * ev.y; eacc[7].z += p1.w * ev.z; eacc[7].w += p1.w * ev.w;
            }
        }
        if (t < 64) {
            const int h = t & 7, part = t >> 3;
            float s = 0.f;
            const int rb = part * 16;
            for (int r = 0; r < 16; ++r) s += pt[(rb + r) * 8 + h];
            redh[part * 9 + h] = s;
        }
        __syncthreads();
        // post-barrier lh update: redh/al not overwritten until t<8 pass the
        // next tile's first barrier (see R4 note) — safe.
        if (t < 8) {
            float s = 0.f;
            for (int p = 0; p < 8; ++p) s += redh[p * 9 + t];
            lh[t] = lh[t] * al[t] + s;
        }
    }

    // ---- reduce 32 slice-partials in two stages (Et holds 16 slices) ----
    if (sl >= 16) {
        #pragma unroll
        for (int h = 0; h < 8; ++h) Et[(sl - 16) * 256 + h * 32 + c4] = eacc[h];
    }
    __syncthreads();
    if (sl < 16) {
        #pragma unroll
        for (int h = 0; h < 8; ++h) {
            const float4 o = Et[sl * 256 + h * 32 + c4];
            eacc[h].x += o.x; eacc[h].y += o.y; eacc[h].z += o.z; eacc[h].w += o.w;
            Et[sl * 256 + h * 32 + c4] = eacc[h];
        }
    }
    __syncthreads();
    if (t < 256) {
        const int h = t >> 5, cc = t & 31;
        float4 s = make_float4(0.f, 0.f, 0.f, 0.f);
        #pragma unroll
        for (int s2 = 0; s2 < 16; ++s2) {
            const float4 v = Et[s2 * 256 + h * 32 + cc];
            s.x += v.x; s.y += v.y; s.z += v.z; s.w += v.w;
        }
        const float invl = 1.0f / lh[h];
        EbarF4[h * 32 + cc] = make_float4(s.x * invl, s.y * invl, s.z * invl, s.w * invl);
    }
    __syncthreads();

    // ---- Phase D: heads -> glimpse -> gp, 8-way k-split each ----
    {
        const int part = t >> 7, d = t & 127, h = d >> 4;
        float acc = 0.f;
        const int c0 = part * 16;
        for (int c = c0; c < c0 + 16; ++c) acc += EbarF[h * 128 + c] * Wn[c * 384 + 128 + d];
        qred[part][d] = acc;
    }
    __syncthreads();
    if (t < 128) {
        float acc = 0.f;
        #pragma unroll
        for (int p = 0; p < 8; ++p) acc += qred[p][t];
        heads[t] = acc;
    }
    __syncthreads();
    {
        const int part = t >> 7, d = t & 127;
        float acc = 0.f;
        const int j0 = part * 16;
        for (int j = j0; j < j0 + 16; ++j) acc += heads[j] * Wo[j * 128 + d];
        qred[part][d] = acc;
    }
    __syncthreads();
    if (t < 128) {
        float acc = 0.f;
        #pragma unroll
        for (int p = 0; p < 8; ++p) acc += qred[p][t];
        gl[t] = acc;
    }
    __syncthreads();
    {
        const int part = t >> 7, c = t & 127;
        float acc = 0.f;
        const int d0 = part * 16;
        for (int d = d0; d < d0 + 16; ++d) acc += Wn[c * 384 + 256 + d] * gl[d];
        qred[part][c] = acc;
    }
    __syncthreads();
    if (t < 128) {
        float acc = 0.f;
        #pragma unroll
        for (int p = 0; p < 8; ++p) acc += qred[p][t];
        gp[t] = acc * 0.08838834764831845f;   // 1/sqrt(128)
    }
    __syncthreads();

    // ---- Phase E: logits + log_softmax (z := pt, partials := ct) ----
    {
        const int row = t >> 3, sub = t & 7;
        for (int tile = 0; tile < 8; ++tile) {
            const int g = tile * 128 + row;
            float acc = 0.f;
            if (g < 1000) {
                #pragma unroll
                for (int i = 0; i < 4; ++i) {
                    const float4 v = E4[g * 32 + sub * 4 + i];
                    const float4 w = gp4[sub * 4 + i];
                    acc += v.x * w.x + v.y * w.y + v.z * w.z + v.w * w.w;
                }
            }
            ct[row * 9 + sub] = acc;
            __syncthreads();
            if (t < 128) {
                const int g2 = tile * 128 + t;
                if (g2 < 1000) {
                    float s = 0.f;
                    #pragma unroll
                    for (int k = 0; k < 8; ++k) s += ct[t * 9 + k];
                    float zz = 10.0f * tanhf(s);
                    const bool m = useB ? (maskB[b * 1000 + g2] != 0)
                                        : (maskI[b * 1000 + g2] != 0);
                    if (m) zz = NEG;
                    pt[g2] = zz;
                }
            }
            __syncthreads();
        }
    }
    float v = (t < 1000) ? pt[t] : -3e38f;
    #pragma unroll
    for (int off = 32; off > 0; off >>= 1) v = fmaxf(v, __shfl_down(v, off, 64));
    if ((t & 63) == 0) red[t >> 6] = v;
    __syncthreads();
    if (t == 0) {
        float m = red[0];
        for (int i = 1; i < 16; ++i) m = fmaxf(m, red[i]);
        stat[0] = m;
    }
    __syncthreads();
    float sv = (t < 1000) ? __expf(pt[t] - stat[0]) : 0.f;
    #pragma unroll
    for (int off = 32; off > 0; off >>= 1) sv += __shfl_down(sv, off, 64);
    if ((t & 63) == 0) red[t >> 6] = sv;
    __syncthreads();
    if (t == 0) {
        float s = 0.f;
        for (int i = 0; i < 16; ++i) s += red[i];
        stat[1] = stat[0] + __logf(s);
    }
    __syncthreads();
    if (t < 1000)
        out[(size_t)b * 1000 + t] = pt[t] - stat[1];
}

// ---------------------------------------------------------------------------
extern "C" void kernel_launch(void* const* d_in, const int* in_sizes, int n_in,
                              void* d_out, int out_size, void* d_ws, size_t ws_size,
                              hipStream_t stream) {
    const float* E  = (const float*)d_in[0];
    const float* Wn = (const float*)d_in[1];
    const float* Wf = (const float*)d_in[2];
    const float* Ws = (const float*)d_in[3];
    const float* Wo = (const float*)d_in[4];
    const int*   fi = (const int*)d_in[5];
    const int*   li = (const int*)d_in[6];
    const int*   maskI = (const int*)d_in[7];
    const unsigned char* maskB = (const unsigned char*)d_in[7];
    float* out = (float*)d_out;

    k_fused<<<256, 1024, 0, stream>>>(E, Wn, Wf, Ws, Wo, fi, li, maskI, maskB, out);
}